// Round 4
// baseline (236.769 us; speedup 1.0000x reference)
//
#include <hip/hip_runtime.h>
#include <hip/hip_bf16.h>

// VectorQuantize: B=4, N=2048, DIM=256, HEADS=4, CODEBOOK=8192, HD=64
// Established by forensics (R0-R3):
//   inputs  fp32 (x [4,2048,256], embed [4,8192,64])
//   output  fp32 (quantize [4,2048,256] ++ embed_ind [4,2048,4] as float values)
//   (harness bf16-rounds the REFERENCE for thresholding -> thr 163.84, but the
//    d_out buffer itself is fp32: R3's absmax 8193.625 decoded bit-exactly as a
//    bf16 index short pair [0x0000,0x4600] read as the fp32 word 8192.0.)
// Distances: fp32-faithful via 3-way bf16 split MFMA (terms i+j<=2, rel ~2^-24).

#define HEADS    4
#define CODEBOOK 8192
#define HD       64
#define BQ       8192                  // queries per head = B*N
#define QOFF     (4 * 2048 * 256)      // quantize FLOAT elements in d_out
#define NPART    4
#define CPART    (CODEBOOK / NPART)    // 2048 codes per partition
#define NSTAGE   (CPART / 32)          // 64 stages of 32 codes

typedef __bf16 bf16x8 __attribute__((ext_vector_type(8)));
typedef float  f32x4  __attribute__((ext_vector_type(4)));

__device__ float g_y2[HEADS * CODEBOOK];          // 0.5*||e||^2 (exact fp32)
__device__ float g_pval[NPART][HEADS * BQ];       // per-partition best value
__device__ int   g_pidx[NPART][HEADS * BQ];       // per-partition best index

// split fp32 -> 3 bf16 levels, exact: f == (float)b0 + (float)b1 + (float)b2
__device__ inline void split3(float f, __bf16& b0, __bf16& b1, __bf16& b2) {
    b0 = (__bf16)f;
    float r = f - (float)b0;
    b1 = (__bf16)r;
    r -= (float)b1;
    b2 = (__bf16)r;
}

// ---------------- kernel 0: g_y2 = 0.5 * sum_d embed^2 (fp32 exact) --------
__global__ __launch_bounds__(256) void y2_kernel(const float* __restrict__ embed) {
    int id = blockIdx.x * 256 + threadIdx.x;      // h*CODEBOOK + c
    const float* p = embed + (size_t)id * HD;
    float s = 0.f;
#pragma unroll
    for (int i = 0; i < 16; i++) {
        float4 v = *reinterpret_cast<const float4*>(p + i * 4);
        s = fmaf(v.x, v.x, s); s = fmaf(v.y, v.y, s);
        s = fmaf(v.z, v.z, s); s = fmaf(v.w, v.w, s);
    }
    g_y2[id] = 0.5f * s;
}

// ---------------- kernel 1: split-bf16 MFMA distances + argmin -------------
// grid = 1024 = h(4) x qgroup(64) x part(4); block = 256 (4 waves).
// Wave owns 32 queries; block scans one 2048-code partition via LDS stages.
// MFMA 16x16x32_bf16 layouts (HW-verified):
//   A: lane -> A[m=lane&15][k=quad*8+j];  B: lane -> B[k=quad*8+j][n=lane&15]
//   C: lane -> col=lane&15, row=quad*4+reg
__global__ __launch_bounds__(256) void dist_kernel(const float* __restrict__ x,
                                                   const float* __restrict__ embed) {
    __shared__ __align__(16) __bf16 tile[2][3][32 * 72];   // buf x level x (32 codes, 72 stride)

    const int bid  = blockIdx.x;
    const int part = bid & 3;
    const int qgrp = (bid >> 2) & 63;
    const int h    = bid >> 8;
    const int t    = threadIdx.x;
    const int wave = t >> 6;
    const int lane = t & 63;
    const int col  = lane & 15;
    const int quad = lane >> 4;

    const int qbase = qgrp * 128 + wave * 32;
    const int cbase = part * CPART;

    // A fragments: a[rowtile][level][khalf], split on the fly from fp32 x
    bf16x8 a[2][3][2];
    {
        const float* xr = x + ((size_t)(qbase + col) * 256 + h * 64 + quad * 8);
#pragma unroll
        for (int rt = 0; rt < 2; rt++) {
#pragma unroll
            for (int kh = 0; kh < 2; kh++) {
                const float* p = xr + rt * 16 * 256 + kh * 32;
#pragma unroll
                for (int j = 0; j < 8; j++) {
                    __bf16 b0, b1, b2;
                    split3(p[j], b0, b1, b2);
                    a[rt][0][kh][j] = b0;
                    a[rt][1][kh][j] = b1;
                    a[rt][2][kh][j] = b2;
                }
            }
        }
    }

    // codebook staging: thread t owns code t>>3, 8-float granule t&7
    const float* esrc = embed + ((size_t)h * CODEBOOK + cbase) * HD + (size_t)t * 8;
    const int ldst = (t >> 3) * 72 + (t & 7) * 8;          // elements
    float4 pf0 = *reinterpret_cast<const float4*>(esrc);
    float4 pf1 = *reinterpret_cast<const float4*>(esrc + 4);

    const float* y2h = g_y2 + h * CODEBOOK + cbase;

    float bv0[4], bv1[4]; int bc0[4], bc1[4];
#pragma unroll
    for (int r = 0; r < 4; r++) { bv0[r] = bv1[r] = 3.4e38f; bc0[r] = bc1[r] = 0; }

    const int rdoff = col * 72 + quad * 8;

    for (int s = 0; s < NSTAGE; s++) {
        {   // split current stage granule into 3 levels and store to LDS
            float f[8] = {pf0.x, pf0.y, pf0.z, pf0.w, pf1.x, pf1.y, pf1.z, pf1.w};
            bf16x8 v0, v1, v2;
#pragma unroll
            for (int j = 0; j < 8; j++) {
                __bf16 b0, b1, b2;
                split3(f[j], b0, b1, b2);
                v0[j] = b0; v1[j] = b1; v2[j] = b2;
            }
            *reinterpret_cast<bf16x8*>(&tile[s & 1][0][ldst]) = v0;
            *reinterpret_cast<bf16x8*>(&tile[s & 1][1][ldst]) = v1;
            *reinterpret_cast<bf16x8*>(&tile[s & 1][2][ldst]) = v2;
        }
        if (s + 1 < NSTAGE) {
            pf0 = *reinterpret_cast<const float4*>(esrc + (size_t)(s + 1) * 32 * HD);
            pf1 = *reinterpret_cast<const float4*>(esrc + (size_t)(s + 1) * 32 * HD + 4);
        }
        __syncthreads();   // publishes tile[s&1]; buffer-reuse safe (2 buffers, 1 barrier/stage)

#pragma unroll
        for (int inner = 0; inner < 2; inner++) {
            const __bf16* bb = &tile[s & 1][0][inner * 16 * 72 + rdoff];
            bf16x8 b0[2], b1[2], b2[2];                    // [khalf] per level
            b0[0] = *reinterpret_cast<const bf16x8*>(bb);
            b0[1] = *reinterpret_cast<const bf16x8*>(bb + 32);
            b1[0] = *reinterpret_cast<const bf16x8*>(bb + 32 * 72);
            b1[1] = *reinterpret_cast<const bf16x8*>(bb + 32 * 72 + 32);
            b2[0] = *reinterpret_cast<const bf16x8*>(bb + 64 * 72);
            b2[1] = *reinterpret_cast<const bf16x8*>(bb + 64 * 72 + 32);

            f32x4 acc0 = {0.f, 0.f, 0.f, 0.f};
            f32x4 acc1 = {0.f, 0.f, 0.f, 0.f};
#pragma unroll
            for (int kh = 0; kh < 2; kh++) {
                // products (x_i, e_j) with i+j<=2: rel err ~2^-24 (fp32-faithful)
                acc0 = __builtin_amdgcn_mfma_f32_16x16x32_bf16(a[0][0][kh], b0[kh], acc0, 0, 0, 0);
                acc0 = __builtin_amdgcn_mfma_f32_16x16x32_bf16(a[0][0][kh], b1[kh], acc0, 0, 0, 0);
                acc0 = __builtin_amdgcn_mfma_f32_16x16x32_bf16(a[0][1][kh], b0[kh], acc0, 0, 0, 0);
                acc0 = __builtin_amdgcn_mfma_f32_16x16x32_bf16(a[0][0][kh], b2[kh], acc0, 0, 0, 0);
                acc0 = __builtin_amdgcn_mfma_f32_16x16x32_bf16(a[0][1][kh], b1[kh], acc0, 0, 0, 0);
                acc0 = __builtin_amdgcn_mfma_f32_16x16x32_bf16(a[0][2][kh], b0[kh], acc0, 0, 0, 0);
                acc1 = __builtin_amdgcn_mfma_f32_16x16x32_bf16(a[1][0][kh], b0[kh], acc1, 0, 0, 0);
                acc1 = __builtin_amdgcn_mfma_f32_16x16x32_bf16(a[1][0][kh], b1[kh], acc1, 0, 0, 0);
                acc1 = __builtin_amdgcn_mfma_f32_16x16x32_bf16(a[1][1][kh], b0[kh], acc1, 0, 0, 0);
                acc1 = __builtin_amdgcn_mfma_f32_16x16x32_bf16(a[1][0][kh], b2[kh], acc1, 0, 0, 0);
                acc1 = __builtin_amdgcn_mfma_f32_16x16x32_bf16(a[1][1][kh], b1[kh], acc1, 0, 0, 0);
                acc1 = __builtin_amdgcn_mfma_f32_16x16x32_bf16(a[1][2][kh], b0[kh], acc1, 0, 0, 0);
            }

            int   c  = s * 32 + inner * 16 + col;
            float yc = y2h[c];
#pragma unroll
            for (int r = 0; r < 4; r++) {
                float s0 = yc - acc0[r];                   // 0.5*||x-e||^2 - 0.5*||x||^2
                if (s0 < bv0[r]) { bv0[r] = s0; bc0[r] = c; }
                float s1 = yc - acc1[r];
                if (s1 < bv1[r]) { bv1[r] = s1; bc1[r] = c; }
            }
        }
    }

    // reduce across 16 column slots; lexicographic (val, idx) = np first-argmax
#pragma unroll
    for (int r = 0; r < 4; r++) {
        float v0 = bv0[r]; int c0 = bc0[r];
        float v1 = bv1[r]; int c1 = bc1[r];
#pragma unroll
        for (int off = 8; off >= 1; off >>= 1) {
            float ov = __shfl_xor(v0, off, 16); int oc = __shfl_xor(c0, off, 16);
            if (ov < v0 || (ov == v0 && oc < c0)) { v0 = ov; c0 = oc; }
            ov = __shfl_xor(v1, off, 16); oc = __shfl_xor(c1, off, 16);
            if (ov < v1 || (ov == v1 && oc < c1)) { v1 = ov; c1 = oc; }
        }
        if (col == 0) {
            int q0 = h * BQ + qbase + quad * 4 + r;
            g_pval[part][q0] = v0; g_pidx[part][q0] = cbase + c0;
            int q1 = q0 + 16;
            g_pval[part][q1] = v1; g_pidx[part][q1] = cbase + c1;
        }
    }
}

// ---------------- kernel 2: merge partitions + gather + index write --------
// FP32 output layout: quantize[m][h*64+d] floats, then indices as floats.
__global__ __launch_bounds__(256) void merge_kernel(const float* __restrict__ embed,
                                                    float* __restrict__ out) {
    int id = blockIdx.x * 256 + threadIdx.x;   // m*4 + h  (m-major, coalesced idx write)
    int m = id >> 2;
    int h = id & 3;
    int q = h * BQ + m;

    float bv = g_pval[0][q]; int bc = g_pidx[0][q];
#pragma unroll
    for (int p = 1; p < NPART; p++) {
        float v = g_pval[p][q]; int c = g_pidx[p][q];
        if (v < bv || (v == bv && c < bc)) { bv = v; bc = c; }
    }

    out[QOFF + id] = (float)bc;                // embed_ind[b][n][h] as fp32 value

    int idx = bc & (CODEBOOK - 1);             // defensive in-range
    const float* src = embed + ((size_t)h * CODEBOOK + idx) * HD;
    float*       dst = out + (size_t)m * 256 + h * 64;
#pragma unroll
    for (int i = 0; i < 16; i++)               // 64 fp32, verbatim
        *reinterpret_cast<float4*>(dst + i * 4) = *reinterpret_cast<const float4*>(src + i * 4);
}

extern "C" void kernel_launch(void* const* d_in, const int* in_sizes, int n_in,
                              void* d_out, int out_size, void* d_ws, size_t ws_size,
                              hipStream_t stream) {
    const float* x     = (const float*)d_in[0];
    const float* embed = (const float*)d_in[1];
    float*       out   = (float*)d_out;

    y2_kernel  <<<128,  256, 0, stream>>>(embed);
    dist_kernel<<<1024, 256, 0, stream>>>(x, embed);
    merge_kernel<<<128, 256, 0, stream>>>(embed, out);
}

// Round 5
// 221.244 us; speedup vs baseline: 1.0702x; 1.0702x over previous
//
#include <hip/hip_runtime.h>
#include <hip/hip_bf16.h>

// VectorQuantize: B=4, N=2048, DIM=256, HEADS=4, CODEBOOK=8192, HD=64
// Established (R0-R4): inputs fp32, output fp32 (quantize ++ indices-as-floats).
// Distances fp32-faithful via 3-way bf16 split MFMA (6 terms i+j<=2, rel ~2^-24).
// R4 passed (absmax 0) at 177 us dist. R5: 64 q/wave (halves LDS reads),
// XOR-swizzled stride-64 LDS (kills the 1.26e7 bank conflicts), pipelined
// K-loop (prefetch latency hidden behind compute, single barrier/stage).

#define HEADS    4
#define CODEBOOK 8192
#define HD       64
#define BQ       8192                  // queries per head = B*N
#define QOFF     (4 * 2048 * 256)      // quantize FLOAT elements in d_out
#define NPART    4
#define CPART    (CODEBOOK / NPART)    // 2048 codes per partition
#define NSTAGE   (CPART / 32)          // 64 stages of 32 codes

typedef __bf16 bf16x8 __attribute__((ext_vector_type(8)));
typedef float  f32x4  __attribute__((ext_vector_type(4)));

__device__ float g_y2[HEADS * CODEBOOK];          // 0.5*||e||^2 (exact fp32)
__device__ float g_pval[NPART][HEADS * BQ];       // per-partition best value
__device__ int   g_pidx[NPART][HEADS * BQ];       // per-partition best index

// split fp32 -> 3 bf16 levels, exact: f == (float)b0 + (float)b1 + (float)b2
__device__ inline void split3(float f, __bf16& b0, __bf16& b1, __bf16& b2) {
    b0 = (__bf16)f;
    float r = f - (float)b0;
    b1 = (__bf16)r;
    r -= (float)b1;
    b2 = (__bf16)r;
}

// ---------------- kernel 0: g_y2 = 0.5 * sum_d embed^2 (fp32 exact) --------
__global__ __launch_bounds__(256) void y2_kernel(const float* __restrict__ embed) {
    int id = blockIdx.x * 256 + threadIdx.x;      // h*CODEBOOK + c
    const float* p = embed + (size_t)id * HD;
    float s = 0.f;
#pragma unroll
    for (int i = 0; i < 16; i++) {
        float4 v = *reinterpret_cast<const float4*>(p + i * 4);
        s = fmaf(v.x, v.x, s); s = fmaf(v.y, v.y, s);
        s = fmaf(v.z, v.z, s); s = fmaf(v.w, v.w, s);
    }
    g_y2[id] = 0.5f * s;
}

// ---------------- kernel 1: split-bf16 MFMA distances + argmin -------------
// grid = 512 = part(4) x qgroup(32) x head(4); block = 256 (4 waves).
// Each wave owns 64 queries (4 pinned A row-tiles); block scans one 2048-code
// partition in 64 stages of 32 codes through double-buffered, XOR-swizzled LDS.
// LDS layout per buffer: [level][row(32)][64 bf16], 16B granule g of row r
// stored at g^(r&7)  -> both ds_write_b128 and ds_read_b128 conflict-free.
// MFMA 16x16x32_bf16 layouts (HW-verified):
//   A: lane -> A[m=lane&15][k=quad*8+j];  B: lane -> B[k=quad*8+j][n=lane&15]
//   C: lane -> col=lane&15, row=quad*4+reg
__global__ __launch_bounds__(256, 2) void dist_kernel(const float* __restrict__ x,
                                                      const float* __restrict__ embed) {
    __shared__ __align__(16) __bf16 tile[2][3][32 * 64];   // 24576 B

    const int bid  = blockIdx.x;
    const int part = bid & 3;
    const int qg   = (bid >> 2) & 31;
    const int h    = bid >> 7;
    const int t    = threadIdx.x;
    const int wave = t >> 6;
    const int lane = t & 63;
    const int col  = lane & 15;
    const int quad = lane >> 4;

    const int qbase = qg * 256 + wave * 64;       // this wave's 64 queries
    const int cbase = part * CPART;

    // A fragments a[rowtile][level][khalf], split on the fly from fp32 x
    bf16x8 a[4][3][2];
#pragma unroll
    for (int rt = 0; rt < 4; rt++) {
#pragma unroll
        for (int kh = 0; kh < 2; kh++) {
            const float* p = x + ((size_t)(qbase + rt * 16 + col) * 256 + h * 64 + kh * 32 + quad * 8);
#pragma unroll
            for (int j = 0; j < 8; j++) {
                __bf16 b0, b1, b2;
                split3(p[j], b0, b1, b2);
                a[rt][0][kh][j] = b0;
                a[rt][1][kh][j] = b1;
                a[rt][2][kh][j] = b2;
            }
        }
    }

    // staging: thread t owns code-row t>>3, granule t&7 (8 floats) of each stage
    const float* esrc = embed + ((size_t)h * CODEBOOK + cbase) * HD + (size_t)t * 8;
    const int row  = t >> 3;
    const int gsw  = (t & 7) ^ (row & 7);                  // swizzled granule
    const int ldst = row * 64 + gsw * 8;                   // shorts, within a level plane

    const float* y2h = g_y2 + h * CODEBOOK + cbase;

    float bv[4][4]; int bc[4][4];
#pragma unroll
    for (int rt = 0; rt < 4; rt++)
#pragma unroll
        for (int r = 0; r < 4; r++) { bv[rt][r] = 3.4e38f; bc[rt][r] = 0; }

    // helper: split pf regs -> 3 LDS planes of buffer `buf`
    auto stage_write = [&](int buf, float4 pf0, float4 pf1) {
        float f[8] = {pf0.x, pf0.y, pf0.z, pf0.w, pf1.x, pf1.y, pf1.z, pf1.w};
        bf16x8 v0, v1, v2;
#pragma unroll
        for (int j = 0; j < 8; j++) {
            __bf16 b0, b1, b2;
            split3(f[j], b0, b1, b2);
            v0[j] = b0; v1[j] = b1; v2[j] = b2;
        }
        *reinterpret_cast<bf16x8*>(&tile[buf][0][ldst]) = v0;
        *reinterpret_cast<bf16x8*>(&tile[buf][1][ldst]) = v1;
        *reinterpret_cast<bf16x8*>(&tile[buf][2][ldst]) = v2;
    };

    // preamble: stage 0 into buf0, preload stage 1, publish
    float4 pf0 = *reinterpret_cast<const float4*>(esrc);
    float4 pf1 = *reinterpret_cast<const float4*>(esrc + 4);
    stage_write(0, pf0, pf1);
    pf0 = *reinterpret_cast<const float4*>(esrc + 2048);
    pf1 = *reinterpret_cast<const float4*>(esrc + 2048 + 4);
    __syncthreads();

    const int swbase = col & 7;                            // read-side swizzle key

    for (int s = 0; s < NSTAGE; s++) {
        // write stage s+1 (regs -> other buffer), then issue load of stage s+2.
        // Safe: buffer (s+1)&1 was last read at stage s-1, before the previous
        // barrier. The in-flight load is drained at THIS stage's end barrier,
        // i.e. after a full stage of compute -> latency hidden.
        if (s + 1 < NSTAGE) stage_write((s + 1) & 1, pf0, pf1);
        if (s + 2 < NSTAGE) {
            pf0 = *reinterpret_cast<const float4*>(esrc + (size_t)(s + 2) * 2048);
            pf1 = *reinterpret_cast<const float4*>(esrc + (size_t)(s + 2) * 2048 + 4);
        }

#pragma unroll
        for (int inner = 0; inner < 2; inner++) {
            const int rbase = (inner * 16 + col) * 64;     // row offset in plane (shorts)
            bf16x8 b[3][2];
#pragma unroll
            for (int lvl = 0; lvl < 3; lvl++)
#pragma unroll
                for (int kh = 0; kh < 2; kh++)
                    b[lvl][kh] = *reinterpret_cast<const bf16x8*>(
                        &tile[s & 1][lvl][rbase + ((((kh << 2) | quad) ^ swbase) << 3)]);

            const int   c  = s * 32 + inner * 16 + col;
            const float yc = y2h[c];
#pragma unroll
            for (int rt = 0; rt < 4; rt++) {
                f32x4 acc = {0.f, 0.f, 0.f, 0.f};
#pragma unroll
                for (int kh = 0; kh < 2; kh++) {
                    acc = __builtin_amdgcn_mfma_f32_16x16x32_bf16(a[rt][0][kh], b[0][kh], acc, 0, 0, 0);
                    acc = __builtin_amdgcn_mfma_f32_16x16x32_bf16(a[rt][0][kh], b[1][kh], acc, 0, 0, 0);
                    acc = __builtin_amdgcn_mfma_f32_16x16x32_bf16(a[rt][1][kh], b[0][kh], acc, 0, 0, 0);
                    acc = __builtin_amdgcn_mfma_f32_16x16x32_bf16(a[rt][0][kh], b[2][kh], acc, 0, 0, 0);
                    acc = __builtin_amdgcn_mfma_f32_16x16x32_bf16(a[rt][1][kh], b[1][kh], acc, 0, 0, 0);
                    acc = __builtin_amdgcn_mfma_f32_16x16x32_bf16(a[rt][2][kh], b[0][kh], acc, 0, 0, 0);
                }
#pragma unroll
                for (int r = 0; r < 4; r++) {
                    float sv = yc - acc[r];                // 0.5*||x-e||^2 - 0.5*||x||^2
                    if (sv < bv[rt][r]) { bv[rt][r] = sv; bc[rt][r] = c; }
                }
            }
        }
        __syncthreads();
    }

    // reduce across 16 column slots; lexicographic (val,idx) = np first-argmax
#pragma unroll
    for (int rt = 0; rt < 4; rt++) {
#pragma unroll
        for (int r = 0; r < 4; r++) {
            float v = bv[rt][r]; int c = bc[rt][r];
#pragma unroll
            for (int off = 8; off >= 1; off >>= 1) {
                float ov = __shfl_xor(v, off, 16); int oc = __shfl_xor(c, off, 16);
                if (ov < v || (ov == v && oc < c)) { v = ov; c = oc; }
            }
            if (col == 0) {
                int q = h * BQ + qbase + rt * 16 + quad * 4 + r;
                g_pval[part][q] = v; g_pidx[part][q] = cbase + c;
            }
        }
    }
}

// ---------------- kernel 2: merge partitions + gather + index write --------
__global__ __launch_bounds__(256) void merge_kernel(const float* __restrict__ embed,
                                                    float* __restrict__ out) {
    int id = blockIdx.x * 256 + threadIdx.x;   // m*4 + h  (m-major, coalesced idx write)
    int m = id >> 2;
    int h = id & 3;
    int q = h * BQ + m;

    float bv = g_pval[0][q]; int bc = g_pidx[0][q];
#pragma unroll
    for (int p = 1; p < NPART; p++) {
        float v = g_pval[p][q]; int c = g_pidx[p][q];
        if (v < bv || (v == bv && c < bc)) { bv = v; bc = c; }
    }

    out[QOFF + id] = (float)bc;                // embed_ind[b][n][h] as fp32 value

    int idx = bc & (CODEBOOK - 1);             // defensive in-range
    const float* src = embed + ((size_t)h * CODEBOOK + idx) * HD;
    float*       dst = out + (size_t)m * 256 + h * 64;
#pragma unroll
    for (int i = 0; i < 16; i++)               // 64 fp32, verbatim
        *reinterpret_cast<float4*>(dst + i * 4) = *reinterpret_cast<const float4*>(src + i * 4);
}

extern "C" void kernel_launch(void* const* d_in, const int* in_sizes, int n_in,
                              void* d_out, int out_size, void* d_ws, size_t ws_size,
                              hipStream_t stream) {
    const float* x     = (const float*)d_in[0];
    const float* embed = (const float*)d_in[1];
    float*       out   = (float*)d_out;

    y2_kernel  <<<128, 256, 0, stream>>>(embed);
    dist_kernel<<<512, 256, 0, stream>>>(x, embed);
    merge_kernel<<<128, 256, 0, stream>>>(embed, out);
}